// Round 15
// baseline (491.843 us; speedup 1.0000x reference)
//
#include <hip/hip_runtime.h>
#include <hip/hip_bf16.h>

#define N_TOK 4096
#define DIM   512
#define HID   1024
#define OUTD  512
#define NEXP  8
#define TOPK  2

#define MT1 72     // max 128-row M-tiles
#define HROWS 9216 // max padded rows
#define L1B (MT1 * 8)
#define K1B (4096 + N_TOK / 4)             // blocks in w1gate kernel
#define YHALF ((size_t)N_TOK * 2 * OUTD)   // elements per K-half partial buffer

typedef __bf16 bf16;
typedef bf16  bf16x8 __attribute__((ext_vector_type(8)));
typedef bf16  bf16x4 __attribute__((ext_vector_type(4)));
typedef float f32x4  __attribute__((ext_vector_type(4)));

__device__ inline f32x4 mfma16(bf16x8 a, bf16x8 b, f32x4 c) {
    return __builtin_amdgcn_mfma_f32_16x16x32_bf16(a, b, c, 0, 0, 0);
}

__device__ inline void gload16(const bf16* g, char* l) {
    __builtin_amdgcn_global_load_lds(
        (const __attribute__((address_space(1))) void*)g,
        (__attribute__((address_space(3))) void*)l, 16, 0, 0);
}

// decode 128-row m-tile mt -> (expert, row base, list offset, count) from counts
__device__ inline void find_tile(const int* cv, int mt, int& e, int& rb, int& i0, int& ce)
{
    int at = 0, base = 0;
    e = 0; rb = 0; i0 = 0; ce = 0;
#pragma unroll
    for (int ee = 0; ee < NEXP; ++ee) {
        int c = cv[ee]; int n1 = (c + 127) >> 7;
        if (mt >= at && mt < at + n1) {
            e = ee; int lt = mt - at; rb = base + lt * 128; i0 = lt * 128; ce = c;
        }
        at += n1; base += n1 << 7;
    }
}

__device__ inline int tiles_total(const int* cv)
{
    int t = 0;
#pragma unroll
    for (int ee = 0; ee < NEXP; ++ee) t += (cv[ee] + 127) >> 7;
    return t;
}

// 32x32 f32 tile transpose -> bf16 (LDS-staged, coalesced both sides)
__device__ inline void transpose32(const float* __restrict__ s, bf16* __restrict__ d,
                                   int C, int R, int c0, int r0, char* ldsb, int tid)
{
    float (*tile)[33] = (float(*)[33])ldsb;
    int tx = tid & 31, ty = tid >> 5;
#pragma unroll
    for (int i = 0; i < 4; ++i)
        tile[ty + i * 8][tx] = s[(size_t)(r0 + ty + i * 8) * C + c0 + tx];
    __syncthreads();
    int dc = tid >> 3, q = tid & 7;
    bf16x4 v;
#pragma unroll
    for (int j = 0; j < 4; ++j) v[j] = (bf16)tile[q * 4 + j][dc];
    *(bf16x4*)(d + (size_t)(c0 + dc) * R + r0 + q * 4) = v;
}

// ------------- K1: W1 transpose + gate; LAST block buckets -------------
// blocks [0,4096): W1 [512][1024] -> W1t [1024][512]
// blocks [4096,5120): gating (4 tokens per block); WgT built in LDS
// tail block (last to finish): bucket pick_e -> counts/tlist (no extra launch)
__global__ __launch_bounds__(256) void w1gate_kernel(
    const float* __restrict__ W1, const float* __restrict__ Wg,
    const float* __restrict__ bg, const float* __restrict__ x,
    bf16* __restrict__ W1t, bf16* __restrict__ xb,
    float* __restrict__ gates_out, float* __restrict__ topi_out,
    int* __restrict__ pick_e, float* __restrict__ pick_w,
    int* __restrict__ counts, int* __restrict__ tlist, int* __restrict__ done)
{
    __shared__ __align__(16) float smem[NEXP * DIM];   // 16 KB (gate) / tile (prep)
    __shared__ int is_last;
    int b = blockIdx.x, tid = threadIdx.x;

    if (b >= 4096) {
        // ---------------- gate path ----------------
        const float4* Wg4 = (const float4*)Wg;
        for (int i = tid; i < DIM * NEXP / 4; i += 256) {
            float4 v = Wg4[i];
#pragma unroll
            for (int j = 0; j < 4; ++j) {
                int idx = i * 4 + j;
                smem[(idx & 7) * DIM + (idx >> 3)] = ((const float*)&v)[j];
            }
        }
        __syncthreads();

        int wave = tid >> 6;
        int lane = tid & 63;
        int n = (b - 4096) * 4 + wave;

        const float4* x4 = (const float4*)(x + (size_t)n * DIM);
        float4 v0 = x4[lane];
        float4 v1 = x4[lane + 64];

        bf16x4 o0 = { (bf16)v0.x, (bf16)v0.y, (bf16)v0.z, (bf16)v0.w };
        bf16x4 o1 = { (bf16)v1.x, (bf16)v1.y, (bf16)v1.z, (bf16)v1.w };
        bf16x4* xb4 = (bf16x4*)(xb + (size_t)n * DIM);
        xb4[lane]      = o0;
        xb4[lane + 64] = o1;

        float acc[NEXP];
#pragma unroll
        for (int e = 0; e < NEXP; ++e) {
            const float4* wr = (const float4*)(smem + e * DIM);
            float4 w0 = wr[lane];
            float4 w1 = wr[lane + 64];
            acc[e] = v0.x * w0.x + v0.y * w0.y + v0.z * w0.z + v0.w * w0.w
                   + v1.x * w1.x + v1.y * w1.y + v1.z * w1.z + v1.w * w1.w;
        }
#pragma unroll
        for (int off = 32; off >= 1; off >>= 1) {
#pragma unroll
            for (int e = 0; e < NEXP; ++e) acc[e] += __shfl_xor(acc[e], off, 64);
        }
#pragma unroll
        for (int e = 0; e < NEXP; ++e) acc[e] += bg[e];

        float m = acc[0];
#pragma unroll
        for (int e = 1; e < NEXP; ++e) m = fmaxf(m, acc[e]);
        float g[NEXP];
        float s = 0.f;
#pragma unroll
        for (int e = 0; e < NEXP; ++e) { g[e] = expf(acc[e] - m); s += g[e]; }
        float inv_s = 1.f / s;
#pragma unroll
        for (int e = 0; e < NEXP; ++e) g[e] *= inv_s;

        if (lane < NEXP) gates_out[n * NEXP + lane] = g[lane];

        if (lane == 0) {
            int m1 = 0;
#pragma unroll
            for (int e = 1; e < NEXP; ++e) if (g[e] > g[m1]) m1 = e;
            int m2 = (m1 == 0) ? 1 : 0;
#pragma unroll
            for (int e = 0; e < NEXP; ++e) if (e != m1 && g[e] > g[m2]) m2 = e;
            float v1g = g[m1], v2g = g[m2];
            float inv = 1.f / (v1g + v2g);
            topi_out[n * TOPK + 0] = (float)m1;
            topi_out[n * TOPK + 1] = (float)m2;
            int2 pe = { m1, m2 };
            float2 pw = { v1g * inv, v2g * inv };
            *(int2*)(pick_e + n * 2) = pe;
            *(float2*)(pick_w + n * 2) = pw;
        }
    } else {
        // ---------------- W1 transpose path ----------------
        int e = b >> 9, rem = b & 511;
        transpose32(W1 + (size_t)e * DIM * HID, W1t + (size_t)e * DIM * HID,
                    HID, DIM, (rem & 31) * 32, (rem >> 5) * 32, (char*)smem, tid);
    }

    // ---- tail-block bucket: last block to finish scans pick_e ----
    __threadfence();          // release this block's stores (device scope)
    __syncthreads();
    if (tid == 0) {
        int old = atomicAdd(done, 1);
        is_last = (old == K1B - 1);
    }
    __syncthreads();
    if (!is_last) return;
    __threadfence();          // acquire: all blocks' pick_e now visible

    __shared__ int cnt[NEXP];
    if (tid < NEXP) cnt[tid] = 0;
    __syncthreads();
    for (int i = tid; i < N_TOK * 2; i += 256) {
        int e = pick_e[i];
        int p = atomicAdd(&cnt[e], 1);
        tlist[e * N_TOK + p] = i;   // pick index: token*2 + slot
    }
    __syncthreads();
    if (tid < NEXP) counts[tid] = cnt[tid];
}

// Swizzled K-inner LDS layout (rule #21): slot(row,kc) = row*4 + (kc ^ h(row)),
// h(row) = (row&3) ^ ((row>>2)&1); LDS dest linear, global source inverse-swizzled,
// ds_read applies same XOR -> 2-way bank aliasing (free).
// Epilogue: C restaged via LDS with 16B-granule XOR swizzle g = ch ^ (row&3);
// global writes are 16 consecutive lanes covering one full 256B row.

// ------------- K2: layer1 (blocks [0,L1B)) + W2 transpose (blocks [L1B,+4096)) ----
__global__ __launch_bounds__(256, 4) void l1_kernel(
    const bf16* __restrict__ xb, const bf16* __restrict__ W1t,
    const float* __restrict__ b1, const int* __restrict__ counts,
    const int* __restrict__ tlist, bf16* __restrict__ h,
    const float* __restrict__ W2, bf16* __restrict__ W2t)
{
    __shared__ __align__(16) char lds[32768];  // 2 bufs x (A 8KB + B 8KB)
    int bid = blockIdx.x, tid = threadIdx.x;

    if (bid >= L1B) {
        // ---------------- W2 transpose path (fills l1's idle slots) ----------
        int t = bid - L1B;
        int e = t >> 9, rem = t & 511;
        transpose32(W2 + (size_t)e * HID * OUTD, W2t + (size_t)e * HID * OUTD,
                    OUTD, HID, (rem & 15) * 32, (rem >> 4) * 32, lds, tid);
        return;
    }

    int cv[NEXP];
#pragma unroll
    for (int ee = 0; ee < NEXP; ++ee) cv[ee] = counts[ee];
    int mt = bid >> 3, nt = bid & 7;
    if (mt >= tiles_total(cv)) return;
    int e, rb, i0, cnt;
    find_tile(cv, mt, e, rb, i0, cnt);

    int w = tid >> 6, l = tid & 63;
    int c0 = w * 128 + l, c1 = c0 + 64;
    int rA0 = c0 >> 2, rA1 = c1 >> 2;
    int kA0 = (c0 & 3) ^ ((rA0 & 3) ^ ((rA0 >> 2) & 1));
    int kA1 = (c1 & 3) ^ ((rA1 & 3) ^ ((rA1 >> 2) & 1));
    int iA0 = i0 + rA0, iA1 = i0 + rA1;
    const int* tl = tlist + e * N_TOK;
    int tok0 = iA0 < cnt ? (tl[iA0] >> 1) : 0;
    int tok1 = iA1 < cnt ? (tl[iA1] >> 1) : 0;
    const bf16* sA0 = xb + (size_t)tok0 * DIM + kA0 * 8;
    const bf16* sA1 = xb + (size_t)tok1 * DIM + kA1 * 8;
    int n0 = nt * 128;
    const bf16* w1e = W1t + (size_t)e * HID * DIM;
    const bf16* sB0 = w1e + (size_t)(n0 + rA0) * DIM + kA0 * 8;
    const bf16* sB1 = w1e + (size_t)(n0 + rA1) * DIM + kA1 * 8;
    int oA0 = c0 * 16, oA1 = c1 * 16;

    f32x4 acc[4][4];
#pragma unroll
    for (int mf = 0; mf < 4; ++mf)
#pragma unroll
        for (int nf = 0; nf < 4; ++nf) acc[mf][nf] = (f32x4){0.f, 0.f, 0.f, 0.f};

    int wm = w >> 1, wn = w & 1;
    int lr = l & 15;
    int kb = ((l >> 4) ^ ((l & 3) ^ ((l >> 2) & 1))) * 16;

    {
        char* A = lds;       char* B = lds + 8192;
        gload16(sA0, A + oA0); gload16(sA1, A + oA1);
        gload16(sB0, B + oA0); gload16(sB1, B + oA1);
    }

    for (int ks = 0; ks < 16; ++ks) {
        __syncthreads();
        if (ks < 15) {
            char* A = lds + (((ks + 1) & 1) * 16384);
            char* B = A + 8192;
            int kof = (ks + 1) * 32;
            gload16(sA0 + kof, A + oA0); gload16(sA1 + kof, A + oA1);
            gload16(sB0 + kof, B + oA0); gload16(sB1 + kof, B + oA1);
        }
        char* A = lds + ((ks & 1) * 16384);
        char* B = A + 8192;
        bf16x8 af[4], bfr[4];
#pragma unroll
        for (int mf = 0; mf < 4; ++mf)
            af[mf] = *(const bf16x8*)(A + (wm * 64 + mf * 16 + lr) * 64 + kb);
#pragma unroll
        for (int nf = 0; nf < 4; ++nf)
            bfr[nf] = *(const bf16x8*)(B + (wn * 64 + nf * 16 + lr) * 64 + kb);
#pragma unroll
        for (int mf = 0; mf < 4; ++mf)
#pragma unroll
            for (int nf = 0; nf < 4; ++nf)
                acc[mf][nf] = mfma16(af[mf], bfr[nf], acc[mf][nf]);
    }

    // epilogue: bias+relu, restage C through LDS, coalesced bf16x8 row stores
    __syncthreads();
    bf16* ct = (bf16*)lds;
    const float* b1e = b1 + e * HID;
#pragma unroll
    for (int nf = 0; nf < 4; ++nf) {
        int col = wn * 64 + nf * 16 + lr;
        float bias = b1e[n0 + col];
#pragma unroll
        for (int mf = 0; mf < 4; ++mf) {
#pragma unroll
            for (int r = 0; r < 4; ++r) {
                int row = wm * 64 + mf * 16 + (l >> 4) * 4 + r;
                float v = fmaxf(acc[mf][nf][r] + bias, 0.f);
                int g = (col >> 3) ^ (row & 3);
                ct[row * 128 + g * 8 + (col & 7)] = (bf16)v;
            }
        }
    }
    __syncthreads();
#pragma unroll
    for (int p = 0; p < 8; ++p) {
        int row = p * 16 + (tid >> 4);
        int ch = tid & 15;
        int g = ch ^ (row & 3);
        bf16x8 v = *(const bf16x8*)(ct + row * 128 + g * 8);
        *(bf16x8*)(h + (size_t)(rb + row) * HID + n0 + ch * 8) = v;
    }
}

// ------------- layer2 (K-split): ypart[half][pick] = h[:,half] @ W2_e[half,:] ----
// grid = MT1*8: mt = b>>3, nt = (b&7)>>1, half = b&1; K=512 per block
__global__ __launch_bounds__(256, 4) void l2_kernel(
    const bf16* __restrict__ h, const bf16* __restrict__ W2t,
    const int* __restrict__ counts, const int* __restrict__ tlist,
    bf16* __restrict__ ybuf)
{
    int cv[NEXP];
#pragma unroll
    for (int ee = 0; ee < NEXP; ++ee) cv[ee] = counts[ee];
    int t = blockIdx.x;
    int mt = t >> 3, nt = (t & 7) >> 1, half = t & 1;
    if (mt >= tiles_total(cv)) return;
    int e, rb, i0, cnt;
    find_tile(cv, mt, e, rb, i0, cnt);
    int k0g = half * 512;

    __shared__ __align__(16) char lds[32768];  // 2 bufs x (A 8KB + B 8KB)

    int tid = threadIdx.x, w = tid >> 6, l = tid & 63;
    int c0 = w * 128 + l, c1 = c0 + 64;
    int rA0 = c0 >> 2, rA1 = c1 >> 2;
    int kA0 = (c0 & 3) ^ ((rA0 & 3) ^ ((rA0 >> 2) & 1));
    int kA1 = (c1 & 3) ^ ((rA1 & 3) ^ ((rA1 >> 2) & 1));
    const bf16* sA0 = h + (size_t)(rb + rA0) * HID + k0g + kA0 * 8;
    const bf16* sA1 = h + (size_t)(rb + rA1) * HID + k0g + kA1 * 8;
    int n0 = nt * 128;
    const bf16* w2e = W2t + (size_t)e * OUTD * HID;
    const bf16* sB0 = w2e + (size_t)(n0 + rA0) * HID + k0g + kA0 * 8;
    const bf16* sB1 = w2e + (size_t)(n0 + rA1) * HID + k0g + kA1 * 8;
    int oA0 = c0 * 16, oA1 = c1 * 16;

    f32x4 acc[4][4];
#pragma unroll
    for (int mf = 0; mf < 4; ++mf)
#pragma unroll
        for (int nf = 0; nf < 4; ++nf) acc[mf][nf] = (f32x4){0.f, 0.f, 0.f, 0.f};

    int wm = w >> 1, wn = w & 1;
    int lr = l & 15;
    int kb = ((l >> 4) ^ ((l & 3) ^ ((l >> 2) & 1))) * 16;

    {
        char* A = lds;       char* B = lds + 8192;
        gload16(sA0, A + oA0); gload16(sA1, A + oA1);
        gload16(sB0, B + oA0); gload16(sB1, B + oA1);
    }

    for (int ks = 0; ks < 16; ++ks) {
        __syncthreads();
        if (ks < 15) {
            char* A = lds + (((ks + 1) & 1) * 16384);
            char* B = A + 8192;
            int kof = (ks + 1) * 32;
            gload16(sA0 + kof, A + oA0); gload16(sA1 + kof, A + oA1);
            gload16(sB0 + kof, B + oA0); gload16(sB1 + kof, B + oA1);
        }
        char* A = lds + ((ks & 1) * 16384);
        char* B = A + 8192;
        bf16x8 af[4], bfr[4];
#pragma unroll
        for (int mf = 0; mf < 4; ++mf)
            af[mf] = *(const bf16x8*)(A + (wm * 64 + mf * 16 + lr) * 64 + kb);
#pragma unroll
        for (int nf = 0; nf < 4; ++nf)
            bfr[nf] = *(const bf16x8*)(B + (wn * 64 + nf * 16 + lr) * 64 + kb);
#pragma unroll
        for (int mf = 0; mf < 4; ++mf)
#pragma unroll
            for (int nf = 0; nf < 4; ++nf)
                acc[mf][nf] = mfma16(af[mf], bfr[nf], acc[mf][nf]);
    }

    // epilogue: restage partial y through LDS, coalesced bf16x8 stores
    __syncthreads();
    bf16* ct = (bf16*)lds;
#pragma unroll
    for (int nf = 0; nf < 4; ++nf) {
        int col = wn * 64 + nf * 16 + lr;
#pragma unroll
        for (int mf = 0; mf < 4; ++mf) {
#pragma unroll
            for (int r = 0; r < 4; ++r) {
                int row = wm * 64 + mf * 16 + (l >> 4) * 4 + r;
                int g = (col >> 3) ^ (row & 3);
                ct[row * 128 + g * 8 + (col & 7)] = (bf16)acc[mf][nf][r];
            }
        }
    }
    __syncthreads();
    const int* tl = tlist + e * N_TOK;
    bf16* yp = ybuf + (size_t)half * YHALF;
#pragma unroll
    for (int p = 0; p < 8; ++p) {
        int row = p * 16 + (tid >> 4);
        int i = i0 + row;
        if (i < cnt) {
            int pi = tl[i];
            int ch = tid & 15;
            int g = ch ^ (row & 3);
            bf16x8 v = *(const bf16x8*)(ct + row * 128 + g * 8);
            *(bf16x8*)(yp + (size_t)pi * OUTD + n0 + ch * 8) = v;
        }
    }
}

// ------------- combine: out[n] = Σ_s w_s * (yp0_s + yp1_s + b2[e_s]) -------------
__global__ __launch_bounds__(256) void combine_kernel(
    const bf16* __restrict__ ybuf, const float* __restrict__ b2,
    const int* __restrict__ pick_e, const float* __restrict__ pick_w,
    float* __restrict__ out)
{
    int wave = threadIdx.x >> 6;
    int lane = threadIdx.x & 63;
    int n = blockIdx.x * 4 + wave;

    int e0 = pick_e[n * 2], e1 = pick_e[n * 2 + 1];
    float w0 = pick_w[n * 2], w1 = pick_w[n * 2 + 1];

    const bf16x8* y0a = (const bf16x8*)(ybuf + (size_t)(n * 2) * OUTD);
    const bf16x8* y0b = (const bf16x8*)(ybuf + YHALF + (size_t)(n * 2) * OUTD);
    const bf16x8* y1a = (const bf16x8*)(ybuf + (size_t)(n * 2 + 1) * OUTD);
    const bf16x8* y1b = (const bf16x8*)(ybuf + YHALF + (size_t)(n * 2 + 1) * OUTD);
    const float4* b20 = (const float4*)(b2 + e0 * OUTD);
    const float4* b21 = (const float4*)(b2 + e1 * OUTD);
    float4* o4 = (float4*)(out + (size_t)n * OUTD);

    bf16x8 a0 = y0a[lane], a1 = y0b[lane];
    bf16x8 bb0 = y1a[lane], bb1 = y1b[lane];
    float4 c0 = b20[lane * 2], c1 = b20[lane * 2 + 1];
    float4 d0 = b21[lane * 2], d1 = b21[lane * 2 + 1];

    float ya[8], yb[8];
#pragma unroll
    for (int j = 0; j < 8; ++j) {
        ya[j] = (float)a0[j] + (float)a1[j];
        yb[j] = (float)bb0[j] + (float)bb1[j];
    }

    float4 r0, r1;
    r0.x = w0 * (ya[0] + c0.x) + w1 * (yb[0] + d0.x);
    r0.y = w0 * (ya[1] + c0.y) + w1 * (yb[1] + d0.y);
    r0.z = w0 * (ya[2] + c0.z) + w1 * (yb[2] + d0.z);
    r0.w = w0 * (ya[3] + c0.w) + w1 * (yb[3] + d0.w);
    r1.x = w0 * (ya[4] + c1.x) + w1 * (yb[4] + d1.x);
    r1.y = w0 * (ya[5] + c1.y) + w1 * (yb[5] + d1.y);
    r1.z = w0 * (ya[6] + c1.z) + w1 * (yb[6] + d1.z);
    r1.w = w0 * (ya[7] + c1.w) + w1 * (yb[7] + d1.w);
    o4[lane * 2]     = r0;
    o4[lane * 2 + 1] = r1;
}

extern "C" void kernel_launch(void* const* d_in, const int* in_sizes, int n_in,
                              void* d_out, int out_size, void* d_ws, size_t ws_size,
                              hipStream_t stream)
{
    const float* x  = (const float*)d_in[0];
    const float* W1 = (const float*)d_in[1];
    const float* b1 = (const float*)d_in[2];
    const float* W2 = (const float*)d_in[3];
    const float* b2 = (const float*)d_in[4];
    const float* Wg = (const float*)d_in[5];
    const float* bg = (const float*)d_in[6];

    float* out_f   = (float*)d_out;
    float* gates_o = out_f + (size_t)N_TOK * OUTD;
    float* topi_o  = gates_o + (size_t)N_TOK * NEXP;

    char* ws = (char*)d_ws;
    size_t offW1t = 0;                                            // 8 MB
    size_t offW2t = offW1t + (size_t)NEXP * HID * DIM * 2;        // 8 MB
    size_t offXb  = offW2t + (size_t)NEXP * OUTD * HID * 2;       // 4 MB
    size_t offH   = offXb + (size_t)N_TOK * DIM * 2;              // 18.9 MB
    size_t offYb  = offH + (size_t)HROWS * HID * 2;               // 16 MB (2 halves)
    size_t offCnt = offYb + 2 * YHALF * 2;
    size_t offTl  = offCnt + 256;
    size_t offPkE = offTl + (size_t)NEXP * N_TOK * 4;
    size_t offPkW = offPkE + (size_t)N_TOK * 2 * 4;
    size_t offDn  = offPkW + (size_t)N_TOK * 2 * 4;

    bf16*  W1t    = (bf16*)(ws + offW1t);
    bf16*  W2t    = (bf16*)(ws + offW2t);
    bf16*  xbuf   = (bf16*)(ws + offXb);
    bf16*  hbuf   = (bf16*)(ws + offH);
    bf16*  ybuf   = (bf16*)(ws + offYb);
    int*   cnts   = (int*)(ws + offCnt);
    int*   tlist  = (int*)(ws + offTl);
    int*   pick_e = (int*)(ws + offPkE);
    float* pick_w = (float*)(ws + offPkW);
    int*   done   = (int*)(ws + offDn);

    hipMemsetAsync(done, 0, sizeof(int), stream);

    w1gate_kernel<<<K1B, 256, 0, stream>>>(
        W1, Wg, bg, x, W1t, xbuf, gates_o, topi_o, pick_e, pick_w,
        cnts, tlist, done);

    l1_kernel<<<L1B + 4096, 256, 0, stream>>>(
        xbuf, W1t, b1, cnts, tlist, hbuf, W2, W2t);

    l2_kernel<<<MT1 * 8, 256, 0, stream>>>(hbuf, W2t, cnts, tlist, ybuf);

    combine_kernel<<<N_TOK / 4, 256, 0, stream>>>(ybuf, b2, pick_e, pick_w, out_f);
}

// Round 16
// 74.753 us; speedup vs baseline: 6.5795x; 6.5795x over previous
//
#include <hip/hip_runtime.h>
#include <hip/hip_bf16.h>

#define N_TOK 4096
#define DIM   512
#define HID   1024
#define OUTD  512
#define NEXP  8
#define TOPK  2

#define MT1 72     // max 128-row M-tiles
#define HROWS 9216 // max padded rows
#define L1B (MT1 * 8)
#define YHALF ((size_t)N_TOK * 2 * OUTD)   // elements per K-half partial buffer

typedef __bf16 bf16;
typedef bf16  bf16x8 __attribute__((ext_vector_type(8)));
typedef bf16  bf16x4 __attribute__((ext_vector_type(4)));
typedef float f32x4  __attribute__((ext_vector_type(4)));

__device__ inline f32x4 mfma16(bf16x8 a, bf16x8 b, f32x4 c) {
    return __builtin_amdgcn_mfma_f32_16x16x32_bf16(a, b, c, 0, 0, 0);
}

__device__ inline void gload16(const bf16* g, char* l) {
    __builtin_amdgcn_global_load_lds(
        (const __attribute__((address_space(1))) void*)g,
        (__attribute__((address_space(3))) void*)l, 16, 0, 0);
}

// 32x32 f32 tile transpose -> bf16 (LDS-staged, coalesced both sides)
__device__ inline void transpose32(const float* __restrict__ s, bf16* __restrict__ d,
                                   int C, int R, int c0, int r0, char* ldsb, int tid)
{
    float (*tile)[33] = (float(*)[33])ldsb;
    int tx = tid & 31, ty = tid >> 5;
#pragma unroll
    for (int i = 0; i < 4; ++i)
        tile[ty + i * 8][tx] = s[(size_t)(r0 + ty + i * 8) * C + c0 + tx];
    __syncthreads();
    int dc = tid >> 3, q = tid & 7;
    bf16x4 v;
#pragma unroll
    for (int j = 0; j < 4; ++j) v[j] = (bf16)tile[q * 4 + j][dc];
    *(bf16x4*)(d + (size_t)(c0 + dc) * R + r0 + q * 4) = v;
}

// ------------- K1: W1 transpose + gate -------------
// blocks [0,4096): W1 [512][1024] -> W1t [1024][512]
// blocks [4096,5120): gating (4 tokens per block); WgT built in LDS
__global__ __launch_bounds__(256) void w1gate_kernel(
    const float* __restrict__ W1, const float* __restrict__ Wg,
    const float* __restrict__ bg, const float* __restrict__ x,
    bf16* __restrict__ W1t, bf16* __restrict__ xb,
    float* __restrict__ gates_out, float* __restrict__ topi_out,
    int* __restrict__ pick_e, float* __restrict__ pick_w)
{
    __shared__ __align__(16) float smem[NEXP * DIM];   // 16 KB (gate) / tile (prep)
    int b = blockIdx.x;

    if (b >= 4096) {
        // ---------------- gate path ----------------
        const float4* Wg4 = (const float4*)Wg;
        for (int i = threadIdx.x; i < DIM * NEXP / 4; i += 256) {
            float4 v = Wg4[i];
#pragma unroll
            for (int j = 0; j < 4; ++j) {
                int idx = i * 4 + j;
                smem[(idx & 7) * DIM + (idx >> 3)] = ((const float*)&v)[j];
            }
        }
        __syncthreads();

        int wave = threadIdx.x >> 6;
        int lane = threadIdx.x & 63;
        int n = (b - 4096) * 4 + wave;

        const float4* x4 = (const float4*)(x + (size_t)n * DIM);
        float4 v0 = x4[lane];
        float4 v1 = x4[lane + 64];

        bf16x4 o0 = { (bf16)v0.x, (bf16)v0.y, (bf16)v0.z, (bf16)v0.w };
        bf16x4 o1 = { (bf16)v1.x, (bf16)v1.y, (bf16)v1.z, (bf16)v1.w };
        bf16x4* xb4 = (bf16x4*)(xb + (size_t)n * DIM);
        xb4[lane]      = o0;
        xb4[lane + 64] = o1;

        float acc[NEXP];
#pragma unroll
        for (int e = 0; e < NEXP; ++e) {
            const float4* wr = (const float4*)(smem + e * DIM);
            float4 w0 = wr[lane];
            float4 w1 = wr[lane + 64];
            acc[e] = v0.x * w0.x + v0.y * w0.y + v0.z * w0.z + v0.w * w0.w
                   + v1.x * w1.x + v1.y * w1.y + v1.z * w1.z + v1.w * w1.w;
        }
#pragma unroll
        for (int off = 32; off >= 1; off >>= 1) {
#pragma unroll
            for (int e = 0; e < NEXP; ++e) acc[e] += __shfl_xor(acc[e], off, 64);
        }
#pragma unroll
        for (int e = 0; e < NEXP; ++e) acc[e] += bg[e];

        float m = acc[0];
#pragma unroll
        for (int e = 1; e < NEXP; ++e) m = fmaxf(m, acc[e]);
        float g[NEXP];
        float s = 0.f;
#pragma unroll
        for (int e = 0; e < NEXP; ++e) { g[e] = expf(acc[e] - m); s += g[e]; }
        float inv_s = 1.f / s;
#pragma unroll
        for (int e = 0; e < NEXP; ++e) g[e] *= inv_s;

        if (lane < NEXP) gates_out[n * NEXP + lane] = g[lane];

        if (lane == 0) {
            int m1 = 0;
#pragma unroll
            for (int e = 1; e < NEXP; ++e) if (g[e] > g[m1]) m1 = e;
            int m2 = (m1 == 0) ? 1 : 0;
#pragma unroll
            for (int e = 0; e < NEXP; ++e) if (e != m1 && g[e] > g[m2]) m2 = e;
            float v1g = g[m1], v2g = g[m2];
            float inv = 1.f / (v1g + v2g);
            topi_out[n * TOPK + 0] = (float)m1;
            topi_out[n * TOPK + 1] = (float)m2;
            int2 pe = { m1, m2 };
            float2 pw = { v1g * inv, v2g * inv };
            *(int2*)(pick_e + n * 2) = pe;
            *(float2*)(pick_w + n * 2) = pw;
        }
        return;
    }

    // ---------------- W1 transpose path ----------------
    int e = b >> 9, rem = b & 511;
    transpose32(W1 + (size_t)e * DIM * HID, W1t + (size_t)e * DIM * HID,
                HID, DIM, (rem & 31) * 32, (rem >> 5) * 32, (char*)smem, threadIdx.x);
}

// ------------- bucket + tile scheduler: one block, 1024 threads -------------
__global__ __launch_bounds__(1024) void bucket_sched_kernel(
    const int* __restrict__ pick_e,
    int* __restrict__ counts, int* __restrict__ tlist, int* __restrict__ meta)
{
    __shared__ int cnt[NEXP];
    if (threadIdx.x < NEXP) cnt[threadIdx.x] = 0;
    __syncthreads();
    for (int i = threadIdx.x; i < N_TOK * 2; i += 1024) {
        int e = pick_e[i];
        int p = atomicAdd(&cnt[e], 1);
        tlist[e * N_TOK + p] = i;   // pick index: token*2 + slot
    }
    __syncthreads();
    if (threadIdx.x == 0) {
        int base = 0, t1 = 0;
        for (int e = 0; e < NEXP; ++e) {
            int c = cnt[e];
            counts[e] = c;
            int n1 = (c + 127) >> 7;
            for (int lt = 0; lt < n1; ++lt) {
                meta[2 + t1 * 3]     = e;
                meta[2 + t1 * 3 + 1] = base + lt * 128;
                meta[2 + t1 * 3 + 2] = lt * 128;
                ++t1;
            }
            base += n1 << 7;
        }
        meta[0] = t1;
    }
}

// Swizzled K-inner LDS layout (rule #21): slot(row,kc) = row*4 + (kc ^ h(row)),
// h(row) = (row&3) ^ ((row>>2)&1); LDS dest linear, global source inverse-swizzled,
// ds_read applies same XOR -> 2-way bank aliasing (free).
// Epilogue: C restaged via LDS with 16B-granule XOR swizzle g = ch ^ (row&3);
// global writes are 16 consecutive lanes covering one full 256B row.

// ------------- K3: layer1 (blocks [0,L1B)) + W2 transpose (blocks [L1B,+4096)) ----
__global__ __launch_bounds__(256, 4) void l1_kernel(
    const bf16* __restrict__ xb, const bf16* __restrict__ W1t,
    const float* __restrict__ b1, const int* __restrict__ counts,
    const int* __restrict__ tlist, const int* __restrict__ meta,
    bf16* __restrict__ h,
    const float* __restrict__ W2, bf16* __restrict__ W2t)
{
    __shared__ __align__(16) char lds[32768];  // 2 bufs x (A 8KB + B 8KB)
    int bid = blockIdx.x, tid = threadIdx.x;

    if (bid >= L1B) {
        // ---------------- W2 transpose path (fills l1's idle slots) ----------
        int t = bid - L1B;
        int e = t >> 9, rem = t & 511;
        transpose32(W2 + (size_t)e * HID * OUTD, W2t + (size_t)e * HID * OUTD,
                    OUTD, HID, (rem & 15) * 32, (rem >> 4) * 32, lds, tid);
        return;
    }

    int mt = bid >> 3, nt = bid & 7;
    if (mt >= meta[0]) return;
    const int* s1 = meta + 2 + mt * 3;
    int e = s1[0], rb = s1[1], i0 = s1[2];
    int cnt = counts[e];

    int w = tid >> 6, l = tid & 63;
    int c0 = w * 128 + l, c1 = c0 + 64;
    int rA0 = c0 >> 2, rA1 = c1 >> 2;
    int kA0 = (c0 & 3) ^ ((rA0 & 3) ^ ((rA0 >> 2) & 1));
    int kA1 = (c1 & 3) ^ ((rA1 & 3) ^ ((rA1 >> 2) & 1));
    int iA0 = i0 + rA0, iA1 = i0 + rA1;
    const int* tl = tlist + e * N_TOK;
    int tok0 = iA0 < cnt ? (tl[iA0] >> 1) : 0;
    int tok1 = iA1 < cnt ? (tl[iA1] >> 1) : 0;
    const bf16* sA0 = xb + (size_t)tok0 * DIM + kA0 * 8;
    const bf16* sA1 = xb + (size_t)tok1 * DIM + kA1 * 8;
    int n0 = nt * 128;
    const bf16* w1e = W1t + (size_t)e * HID * DIM;
    const bf16* sB0 = w1e + (size_t)(n0 + rA0) * DIM + kA0 * 8;
    const bf16* sB1 = w1e + (size_t)(n0 + rA1) * DIM + kA1 * 8;
    int oA0 = c0 * 16, oA1 = c1 * 16;

    f32x4 acc[4][4];
#pragma unroll
    for (int mf = 0; mf < 4; ++mf)
#pragma unroll
        for (int nf = 0; nf < 4; ++nf) acc[mf][nf] = (f32x4){0.f, 0.f, 0.f, 0.f};

    int wm = w >> 1, wn = w & 1;
    int lr = l & 15;
    int kb = ((l >> 4) ^ ((l & 3) ^ ((l >> 2) & 1))) * 16;

    {
        char* A = lds;       char* B = lds + 8192;
        gload16(sA0, A + oA0); gload16(sA1, A + oA1);
        gload16(sB0, B + oA0); gload16(sB1, B + oA1);
    }

    for (int ks = 0; ks < 16; ++ks) {
        __syncthreads();
        if (ks < 15) {
            char* A = lds + (((ks + 1) & 1) * 16384);
            char* B = A + 8192;
            int kof = (ks + 1) * 32;
            gload16(sA0 + kof, A + oA0); gload16(sA1 + kof, A + oA1);
            gload16(sB0 + kof, B + oA0); gload16(sB1 + kof, B + oA1);
        }
        char* A = lds + ((ks & 1) * 16384);
        char* B = A + 8192;
        bf16x8 af[4], bfr[4];
#pragma unroll
        for (int mf = 0; mf < 4; ++mf)
            af[mf] = *(const bf16x8*)(A + (wm * 64 + mf * 16 + lr) * 64 + kb);
#pragma unroll
        for (int nf = 0; nf < 4; ++nf)
            bfr[nf] = *(const bf16x8*)(B + (wn * 64 + nf * 16 + lr) * 64 + kb);
#pragma unroll
        for (int mf = 0; mf < 4; ++mf)
#pragma unroll
            for (int nf = 0; nf < 4; ++nf)
                acc[mf][nf] = mfma16(af[mf], bfr[nf], acc[mf][nf]);
    }

    // epilogue: bias+relu, restage C through LDS, coalesced bf16x8 row stores
    __syncthreads();
    bf16* ct = (bf16*)lds;
    const float* b1e = b1 + e * HID;
#pragma unroll
    for (int nf = 0; nf < 4; ++nf) {
        int col = wn * 64 + nf * 16 + lr;
        float bias = b1e[n0 + col];
#pragma unroll
        for (int mf = 0; mf < 4; ++mf) {
#pragma unroll
            for (int r = 0; r < 4; ++r) {
                int row = wm * 64 + mf * 16 + (l >> 4) * 4 + r;
                float v = fmaxf(acc[mf][nf][r] + bias, 0.f);
                int g = (col >> 3) ^ (row & 3);
                ct[row * 128 + g * 8 + (col & 7)] = (bf16)v;
            }
        }
    }
    __syncthreads();
#pragma unroll
    for (int p = 0; p < 8; ++p) {
        int row = p * 16 + (tid >> 4);
        int ch = tid & 15;
        int g = ch ^ (row & 3);
        bf16x8 v = *(const bf16x8*)(ct + row * 128 + g * 8);
        *(bf16x8*)(h + (size_t)(rb + row) * HID + n0 + ch * 8) = v;
    }
}

// ------------- layer2 (K-split): ypart[half][pick] = h[:,half] @ W2_e[half,:] ----
// grid = MT1*8: mt = b>>3, nt = (b&7)>>1, half = b&1; K=512 per block
__global__ __launch_bounds__(256, 4) void l2_kernel(
    const bf16* __restrict__ h, const bf16* __restrict__ W2t,
    const int* __restrict__ counts, const int* __restrict__ tlist,
    const int* __restrict__ meta, bf16* __restrict__ ybuf)
{
    int t = blockIdx.x;
    int mt = t >> 3, nt = (t & 7) >> 1, half = t & 1;
    if (mt >= meta[0]) return;
    const int* s1 = meta + 2 + mt * 3;
    int e = s1[0], rb = s1[1], i0 = s1[2];
    int cnt = counts[e];
    int k0g = half * 512;

    __shared__ __align__(16) char lds[32768];  // 2 bufs x (A 8KB + B 8KB)

    int tid = threadIdx.x, w = tid >> 6, l = tid & 63;
    int c0 = w * 128 + l, c1 = c0 + 64;
    int rA0 = c0 >> 2, rA1 = c1 >> 2;
    int kA0 = (c0 & 3) ^ ((rA0 & 3) ^ ((rA0 >> 2) & 1));
    int kA1 = (c1 & 3) ^ ((rA1 & 3) ^ ((rA1 >> 2) & 1));
    const bf16* sA0 = h + (size_t)(rb + rA0) * HID + k0g + kA0 * 8;
    const bf16* sA1 = h + (size_t)(rb + rA1) * HID + k0g + kA1 * 8;
    int n0 = nt * 128;
    const bf16* w2e = W2t + (size_t)e * OUTD * HID;
    const bf16* sB0 = w2e + (size_t)(n0 + rA0) * HID + k0g + kA0 * 8;
    const bf16* sB1 = w2e + (size_t)(n0 + rA1) * HID + k0g + kA1 * 8;
    int oA0 = c0 * 16, oA1 = c1 * 16;

    f32x4 acc[4][4];
#pragma unroll
    for (int mf = 0; mf < 4; ++mf)
#pragma unroll
        for (int nf = 0; nf < 4; ++nf) acc[mf][nf] = (f32x4){0.f, 0.f, 0.f, 0.f};

    int wm = w >> 1, wn = w & 1;
    int lr = l & 15;
    int kb = ((l >> 4) ^ ((l & 3) ^ ((l >> 2) & 1))) * 16;

    {
        char* A = lds;       char* B = lds + 8192;
        gload16(sA0, A + oA0); gload16(sA1, A + oA1);
        gload16(sB0, B + oA0); gload16(sB1, B + oA1);
    }

    for (int ks = 0; ks < 16; ++ks) {
        __syncthreads();
        if (ks < 15) {
            char* A = lds + (((ks + 1) & 1) * 16384);
            char* B = A + 8192;
            int kof = (ks + 1) * 32;
            gload16(sA0 + kof, A + oA0); gload16(sA1 + kof, A + oA1);
            gload16(sB0 + kof, B + oA0); gload16(sB1 + kof, B + oA1);
        }
        char* A = lds + ((ks & 1) * 16384);
        char* B = A + 8192;
        bf16x8 af[4], bfr[4];
#pragma unroll
        for (int mf = 0; mf < 4; ++mf)
            af[mf] = *(const bf16x8*)(A + (wm * 64 + mf * 16 + lr) * 64 + kb);
#pragma unroll
        for (int nf = 0; nf < 4; ++nf)
            bfr[nf] = *(const bf16x8*)(B + (wn * 64 + nf * 16 + lr) * 64 + kb);
#pragma unroll
        for (int mf = 0; mf < 4; ++mf)
#pragma unroll
            for (int nf = 0; nf < 4; ++nf)
                acc[mf][nf] = mfma16(af[mf], bfr[nf], acc[mf][nf]);
    }

    // epilogue: restage partial y through LDS, coalesced bf16x8 stores
    __syncthreads();
    bf16* ct = (bf16*)lds;
#pragma unroll
    for (int nf = 0; nf < 4; ++nf) {
        int col = wn * 64 + nf * 16 + lr;
#pragma unroll
        for (int mf = 0; mf < 4; ++mf) {
#pragma unroll
            for (int r = 0; r < 4; ++r) {
                int row = wm * 64 + mf * 16 + (l >> 4) * 4 + r;
                int g = (col >> 3) ^ (row & 3);
                ct[row * 128 + g * 8 + (col & 7)] = (bf16)acc[mf][nf][r];
            }
        }
    }
    __syncthreads();
    const int* tl = tlist + e * N_TOK;
    bf16* yp = ybuf + (size_t)half * YHALF;
#pragma unroll
    for (int p = 0; p < 8; ++p) {
        int row = p * 16 + (tid >> 4);
        int i = i0 + row;
        if (i < cnt) {
            int pi = tl[i];
            int ch = tid & 15;
            int g = ch ^ (row & 3);
            bf16x8 v = *(const bf16x8*)(ct + row * 128 + g * 8);
            *(bf16x8*)(yp + (size_t)pi * OUTD + n0 + ch * 8) = v;
        }
    }
}

// ------------- combine: out[n] = Σ_s w_s * (yp0_s + yp1_s + b2[e_s]) -------------
__global__ __launch_bounds__(256) void combine_kernel(
    const bf16* __restrict__ ybuf, const float* __restrict__ b2,
    const int* __restrict__ pick_e, const float* __restrict__ pick_w,
    float* __restrict__ out)
{
    int wave = threadIdx.x >> 6;
    int lane = threadIdx.x & 63;
    int n = blockIdx.x * 4 + wave;

    int e0 = pick_e[n * 2], e1 = pick_e[n * 2 + 1];
    float w0 = pick_w[n * 2], w1 = pick_w[n * 2 + 1];

    const bf16x8* y0a = (const bf16x8*)(ybuf + (size_t)(n * 2) * OUTD);
    const bf16x8* y0b = (const bf16x8*)(ybuf + YHALF + (size_t)(n * 2) * OUTD);
    const bf16x8* y1a = (const bf16x8*)(ybuf + (size_t)(n * 2 + 1) * OUTD);
    const bf16x8* y1b = (const bf16x8*)(ybuf + YHALF + (size_t)(n * 2 + 1) * OUTD);
    const float4* b20 = (const float4*)(b2 + e0 * OUTD);
    const float4* b21 = (const float4*)(b2 + e1 * OUTD);
    float4* o4 = (float4*)(out + (size_t)n * OUTD);

    bf16x8 a0 = y0a[lane], a1 = y0b[lane];
    bf16x8 bb0 = y1a[lane], bb1 = y1b[lane];
    float4 c0 = b20[lane * 2], c1 = b20[lane * 2 + 1];
    float4 d0 = b21[lane * 2], d1 = b21[lane * 2 + 1];

    float ya[8], yb[8];
#pragma unroll
    for (int j = 0; j < 8; ++j) {
        ya[j] = (float)a0[j] + (float)a1[j];
        yb[j] = (float)bb0[j] + (float)bb1[j];
    }

    float4 r0, r1;
    r0.x = w0 * (ya[0] + c0.x) + w1 * (yb[0] + d0.x);
    r0.y = w0 * (ya[1] + c0.y) + w1 * (yb[1] + d0.y);
    r0.z = w0 * (ya[2] + c0.z) + w1 * (yb[2] + d0.z);
    r0.w = w0 * (ya[3] + c0.w) + w1 * (yb[3] + d0.w);
    r1.x = w0 * (ya[4] + c1.x) + w1 * (yb[4] + d1.x);
    r1.y = w0 * (ya[5] + c1.y) + w1 * (yb[5] + d1.y);
    r1.z = w0 * (ya[6] + c1.z) + w1 * (yb[6] + d1.z);
    r1.w = w0 * (ya[7] + c1.w) + w1 * (yb[7] + d1.w);
    o4[lane * 2]     = r0;
    o4[lane * 2 + 1] = r1;
}

extern "C" void kernel_launch(void* const* d_in, const int* in_sizes, int n_in,
                              void* d_out, int out_size, void* d_ws, size_t ws_size,
                              hipStream_t stream)
{
    const float* x  = (const float*)d_in[0];
    const float* W1 = (const float*)d_in[1];
    const float* b1 = (const float*)d_in[2];
    const float* W2 = (const float*)d_in[3];
    const float* b2 = (const float*)d_in[4];
    const float* Wg = (const float*)d_in[5];
    const float* bg = (const float*)d_in[6];

    float* out_f   = (float*)d_out;
    float* gates_o = out_f + (size_t)N_TOK * OUTD;
    float* topi_o  = gates_o + (size_t)N_TOK * NEXP;

    char* ws = (char*)d_ws;
    size_t offW1t = 0;                                            // 8 MB
    size_t offW2t = offW1t + (size_t)NEXP * HID * DIM * 2;        // 8 MB
    size_t offXb  = offW2t + (size_t)NEXP * OUTD * HID * 2;       // 4 MB
    size_t offH   = offXb + (size_t)N_TOK * DIM * 2;              // 18.9 MB
    size_t offYb  = offH + (size_t)HROWS * HID * 2;               // 16 MB (2 halves)
    size_t offCnt = offYb + 2 * YHALF * 2;
    size_t offTl  = offCnt + 256;
    size_t offMeta = offTl + (size_t)NEXP * N_TOK * 4;
    size_t offPkE = offMeta + 4096;
    size_t offPkW = offPkE + (size_t)N_TOK * 2 * 4;

    bf16*  W1t    = (bf16*)(ws + offW1t);
    bf16*  W2t    = (bf16*)(ws + offW2t);
    bf16*  xbuf   = (bf16*)(ws + offXb);
    bf16*  hbuf   = (bf16*)(ws + offH);
    bf16*  ybuf   = (bf16*)(ws + offYb);
    int*   cnts   = (int*)(ws + offCnt);
    int*   tlist  = (int*)(ws + offTl);
    int*   meta   = (int*)(ws + offMeta);
    int*   pick_e = (int*)(ws + offPkE);
    float* pick_w = (float*)(ws + offPkW);

    w1gate_kernel<<<4096 + N_TOK / 4, 256, 0, stream>>>(
        W1, Wg, bg, x, W1t, xbuf, gates_o, topi_o, pick_e, pick_w);

    bucket_sched_kernel<<<1, 1024, 0, stream>>>(pick_e, cnts, tlist, meta);

    l1_kernel<<<L1B + 4096, 256, 0, stream>>>(
        xbuf, W1t, b1, cnts, tlist, meta, hbuf, W2, W2t);

    l2_kernel<<<MT1 * 8, 256, 0, stream>>>(hbuf, W2t, cnts, tlist, meta, ybuf);

    combine_kernel<<<N_TOK / 4, 256, 0, stream>>>(ybuf, b2, pick_e, pick_w, out_f);
}